// Round 19
// baseline (602.695 us; speedup 1.0000x reference)
//
#include <hip/hip_runtime.h>

#define NS 32   // n_state
#define NI 16   // n_input
#define NA 48   // n_all
#define TT 64   // horizon
#define HT 32   // half horizon
#define CSZ (NA * NA)      // 2304 floats per C_t
#define NTRI 528           // upper-triangle pairs of 32x32

// ---------------- FAST PATH ----------------
// r17 base (best: 543 us, 256 thr — r18's 512-thr probe regressed) + ONE
// change: intermediates PA/PB/Hs/Kt stored f32 in LDS (accumulate f64,
// P state stays f64). Mechanism: these arrays carry the bulk of per-step
// LDS traffic; f32 halves it. Safety: per-step noise ~6e-8 relative into a
// closed-loop-contracting recursion; the r0/r10 divergence mode was
// ASYMMETRY, eliminated by triangle-mirror writes regardless of precision.
// f64 kept for: sP state, all accumulations, G/GJ inverse (exact 1/piv).
// 4 barriers/step, K_t/P_t f32 to d_ws, barrier forward, parallel mu, f32 out.
__launch_bounds__(256, 1)
__global__ void lqr_fast(const float* __restrict__ Ag,
                         const float* __restrict__ Bg,
                         const float* __restrict__ Cg,
                         const float* __restrict__ x0g,
                         float* __restrict__ out,
                         float* __restrict__ Kall,   // [TT][NI][NS] f32
                         float* __restrict__ Pall)   // [TT][NS][NS] f32
{
    __shared__ float  sXT[TT][NS];      //  8192 B  x trajectory (f32)
    __shared__ float  sA[NS][33];       //  4224 B  A (f32, exact input)
    __shared__ float  sB[NS][17];       //  2176 B  B (f32, exact input)
    __shared__ double sP[NS][33];       //  8448 B  Riccati state (f64!)
    __shared__ float  sPA[NS][33];      //  4224 B  P*A (f32 intermediate)
    __shared__ float  sPB[NS][17];      //  2176 B  P*B (f32 intermediate)
    __shared__ float  sHs[NI][33];      //  2112 B  S^T + B^T P A (f32)
    __shared__ float  sKt[NI][33];      //  2112 B  K_t (f32)
    __shared__ double sGi[NI][17];      //  2176 B  G^{-1} (f64)
    __shared__ double sPp[NS][33];      //  8448 B  Q + A^T P A (f64, symmetric)
    __shared__ short  sTri[NTRI];       //  1056 B  packed (i<<8)|j, i<=j
    __shared__ double sx[2][NS];        //   512 B
    __shared__ double su[NI];           //   128 B   (~46 KB)

    const int tid  = threadIdx.x;
    const int wid  = tid >> 6, lane = tid & 63;
    const int pi   = tid >> 3, pj0 = (tid & 7) * 4, pb0 = (tid & 7) * 2;
    const int ki   = tid >> 4, kj0 = (tid & 15) * 2;

    for (int idx = tid; idx < NS * NS; idx += 256) {
        sA[idx >> 5][idx & 31] = Ag[idx];
        sP[idx >> 5][idx & 31] = 0.0;
    }
    for (int idx = tid; idx < NS * NI; idx += 256)
        sB[idx >> 4][idx & 15] = Bg[idx];
    for (int e = tid; e < NTRI; e += 256) {
        int i = 0, rem = e;
        while (rem >= NS - i) { rem -= NS - i; ++i; }
        sTri[e] = (short)((i << 8) | (i + rem));
    }
    __syncthreads();

    // ---- backward sweep: 64 steps, 4 barriers each ----
    for (int t = TT - 1; t >= 0; --t) {
        const float* Ct = Cg + t * CSZ;

        // phase 1: PA = P*A (4 cols), PB = P*B (2 cols) per thread (ILP-6)
        {
            double a0 = 0, a1 = 0, a2 = 0, a3 = 0, b0 = 0, b1 = 0;
            for (int k = 0; k < NS; ++k) {
                const double p = sP[pi][k];
                a0 += p * (double)sA[k][pj0 + 0]; a1 += p * (double)sA[k][pj0 + 1];
                a2 += p * (double)sA[k][pj0 + 2]; a3 += p * (double)sA[k][pj0 + 3];
                b0 += p * (double)sB[k][pb0 + 0]; b1 += p * (double)sB[k][pb0 + 1];
            }
            sPA[pi][pj0 + 0] = (float)a0; sPA[pi][pj0 + 1] = (float)a1;
            sPA[pi][pj0 + 2] = (float)a2; sPA[pi][pj0 + 3] = (float)a3;
            sPB[pi][pb0 + 0] = (float)b0; sPB[pi][pb0 + 1] = (float)b1;
        }
        __syncthreads();                                   // barrier A

        // phase 2 (overlapped): wave0 -> G^{-1} (register GJ via __shfl, f64);
        //   waves 1-3 -> Hs (512 dots) + Pp triangle (528 dots, mirrored)
        if (wid == 0) {
            const int ri = lane & 15, cg = lane >> 4, jb = cg * 4;
            double g0 = (double)Ct[(NS + ri) * NA + NS + jb + 0];
            double g1 = (double)Ct[(NS + ri) * NA + NS + jb + 1];
            double g2 = (double)Ct[(NS + ri) * NA + NS + jb + 2];
            double g3 = (double)Ct[(NS + ri) * NA + NS + jb + 3];
            for (int k = 0; k < NS; ++k) {
                const double b = (double)sB[k][ri];
                g0 += b * (double)sPB[k][jb + 0]; g1 += b * (double)sPB[k][jb + 1];
                g2 += b * (double)sPB[k][jb + 2]; g3 += b * (double)sPB[k][jb + 3];
            }
#pragma unroll
            for (int k = 0; k < NI; ++k) {
                const double myslot = ((k & 3) == 0) ? g0 : ((k & 3) == 1) ? g1
                                     : ((k & 3) == 2) ? g2 : g3;
                const int    plv  = k + ((k >> 2) << 4);      // lane of (k,k)
                const double piv  = __shfl(myslot, plv, 64);
                const double cv   = __shfl(myslot, ri + ((k >> 2) << 4), 64); // (ri,k)
                const double pr0  = __shfl(g0, k + (cg << 4), 64);            // (k,jb+j)
                const double pr1  = __shfl(g1, k + (cg << 4), 64);
                const double pr2  = __shfl(g2, k + (cg << 4), 64);
                const double pr3  = __shfl(g3, k + (cg << 4), 64);
                const double ip   = 1.0 / piv;
                const bool   rk   = (ri == k);
                g0 = rk ? ((jb + 0 == k) ? ip : pr0 * ip)
                        : ((jb + 0 == k) ? -cv * ip : g0 - cv * pr0 * ip);
                g1 = rk ? ((jb + 1 == k) ? ip : pr1 * ip)
                        : ((jb + 1 == k) ? -cv * ip : g1 - cv * pr1 * ip);
                g2 = rk ? ((jb + 2 == k) ? ip : pr2 * ip)
                        : ((jb + 2 == k) ? -cv * ip : g2 - cv * pr2 * ip);
                g3 = rk ? ((jb + 3 == k) ? ip : pr3 * ip)
                        : ((jb + 3 == k) ? -cv * ip : g3 - cv * pr3 * ip);
            }
            sGi[ri][jb + 0] = g0; sGi[ri][jb + 1] = g1;
            sGi[ri][jb + 2] = g2; sGi[ri][jb + 3] = g3;
        } else {
            const int e0 = tid - 64;
            for (int e = e0; e < NI * NS; e += 192) {
                const int i = e >> 5, j = e & 31;
                double acc = (double)Ct[j * NA + NS + i];
                for (int k = 0; k < NS; ++k)
                    acc += (double)sB[k][i] * (double)sPA[k][j];
                sHs[i][j] = (float)acc;
            }
            for (int e = e0; e < NTRI; e += 192) {
                const int p = sTri[e];
                const int i = p >> 8, j = p & 255;
                double acc = (double)Ct[i * NA + j];
                for (int k = 0; k < NS; ++k)
                    acc += (double)sA[k][i] * (double)sPA[k][j];
                sPp[i][j] = acc;
                sPp[j][i] = acc;       // symmetric by construction
            }
        }
        __syncthreads();                                   // barrier B

        // phase 3: K = G^{-1} Hs (2 cols per thread); f32 K to LDS + d_ws
        {
            double a0 = 0, a1 = 0;
            for (int k = 0; k < NI; ++k) {
                const double g = sGi[ki][k];
                a0 += g * (double)sHs[k][kj0 + 0];
                a1 += g * (double)sHs[k][kj0 + 1];
            }
            sKt[ki][kj0 + 0] = (float)a0; sKt[ki][kj0 + 1] = (float)a1;
            Kall[t * NI * NS + ki * NS + kj0 + 0] = (float)a0;
            Kall[t * NI * NS + ki * NS + kj0 + 1] = (float)a1;
        }
        __syncthreads();                                   // barrier C

        // phase 4: P = Pp - Hs^T K on the upper triangle, write both slots
        // (exact symmetry by construction — load-bearing for stability)
        for (int e = tid; e < NTRI; e += 256) {
            const int p = sTri[e];
            const int i = p >> 8, j = p & 255;
            double a = sPp[i][j];
            for (int k = 0; k < NI; ++k)
                a -= (double)sHs[k][i] * (double)sKt[k][j];
            sP[i][j] = a;
            sP[j][i] = a;
            const float af = (float)a;
            Pall[t * NS * NS + i * NS + j] = af;
            Pall[t * NS * NS + j * NS + i] = af;
        }
        __syncthreads();                                   // barrier D
    }

    // ---- forward rollout: tau (x + u), record x trajectory ----
    if (tid < NS) sx[0][tid] = (double)x0g[tid];
    __syncthreads();
    int cur = 0;
    for (int t = 0; t < TT; ++t) {
        if (tid < NS) {
            const float xv = (float)sx[cur][tid];
            sXT[t][tid] = xv;
            out[t * NA + tid] = xv;
        } else if (tid >= 64 && tid < 64 + NI) {
            const int i = tid - 64;
            const float* Kt = Kall + t * NI * NS + i * NS;
            double acc = 0.0;
            for (int k = 0; k < NS; ++k) acc += (double)Kt[k] * sx[cur][k];
            su[i] = -acc;
            out[t * NA + NS + i] = (float)(-acc);
        }
        __syncthreads();
        if (t < TT - 1) {
            if (tid < NS) {
                double acc = 0.0;
                for (int k = 0; k < NS; ++k) acc += (double)sA[tid][k] * sx[cur][k];
                for (int k = 0; k < NI; ++k) acc += (double)sB[tid][k] * su[k];
                sx[cur ^ 1][tid] = acc;
            }
            __syncthreads();
            cur ^= 1;
        }
    }
    __syncthreads();

    // ---- mu pass: mu_t = P_t x_t (2048 parallel dots); mu_0 negated ----
    for (int e = tid; e < TT * NS; e += 256) {
        const int t = e >> 5, i = e & 31;
        const float* Pt = Pall + t * NS * NS + i * NS;
        double acc = 0.0;
        for (int k = 0; k < NS; ++k) acc += (double)Pt[k] * (double)sXT[t][k];
        if (t == 0) acc = -acc;
        out[NA * TT + t * NS + i] = (float)acc;
    }
}

// ---------------- FALLBACK (round-11/12, passing) — if ws_size < 384 KB ----
__launch_bounds__(256, 1)
__global__ void lqr_kernel_fb(const float* __restrict__ Ag,
                              const float* __restrict__ Bg,
                              const float* __restrict__ Cg,
                              const float* __restrict__ x0g,
                              float* __restrict__ out)
{
    __shared__ float  sKh[HT][NI][NS];
    __shared__ float  sXT[TT][NS];
    __shared__ double sA[NS][NS];
    __shared__ double sB[NS][NI];
    __shared__ double sP[NS][NS];
    __shared__ double sPA[NS][NS];
    __shared__ double sPB[NS][NI];
    __shared__ double sHs[NI][NS];
    __shared__ double sKt[NI][NS];
    __shared__ double sGi[NI][NI];
    __shared__ double sPp[NS][NS];
    __shared__ double sx[2][NS];
    __shared__ double su[NI];

    const int tid  = threadIdx.x;
    const int wid  = tid >> 6, lane = tid & 63;
    const int pi   = tid >> 3, pj0 = (tid & 7) * 4, pb0 = (tid & 7) * 2;
    const int ki   = tid >> 4, kj0 = (tid & 15) * 2;

    for (int idx = tid; idx < NS * NS; idx += 256) sA[idx >> 5][idx & 31] = (double)Ag[idx];
    for (int idx = tid; idx < NS * NI; idx += 256) sB[idx >> 4][idx & 15] = (double)Bg[idx];
    __syncthreads();

    auto step = [&](int t, bool storeK, int kbase, bool emitMu) {
        const float* Ct = Cg + t * NA * NA;
        {
            double a0 = 0, a1 = 0, a2 = 0, a3 = 0, b0 = 0, b1 = 0;
            for (int k = 0; k < NS; ++k) {
                const double p = sP[pi][k];
                a0 += p * sA[k][pj0 + 0]; a1 += p * sA[k][pj0 + 1];
                a2 += p * sA[k][pj0 + 2]; a3 += p * sA[k][pj0 + 3];
                b0 += p * sB[k][pb0 + 0]; b1 += p * sB[k][pb0 + 1];
            }
            sPA[pi][pj0 + 0] = a0; sPA[pi][pj0 + 1] = a1;
            sPA[pi][pj0 + 2] = a2; sPA[pi][pj0 + 3] = a3;
            sPB[pi][pb0 + 0] = b0; sPB[pi][pb0 + 1] = b1;
        }
        __syncthreads();
        if (wid == 0) {
            const int ri = lane & 15, cg = lane >> 4, jb = cg * 4;
            double g0 = (double)Ct[(NS + ri) * NA + NS + jb + 0];
            double g1 = (double)Ct[(NS + ri) * NA + NS + jb + 1];
            double g2 = (double)Ct[(NS + ri) * NA + NS + jb + 2];
            double g3 = (double)Ct[(NS + ri) * NA + NS + jb + 3];
            for (int k = 0; k < NS; ++k) {
                const double b = sB[k][ri];
                g0 += b * sPB[k][jb + 0]; g1 += b * sPB[k][jb + 1];
                g2 += b * sPB[k][jb + 2]; g3 += b * sPB[k][jb + 3];
            }
#pragma unroll
            for (int k = 0; k < NI; ++k) {
                const double myslot = ((k & 3) == 0) ? g0 : ((k & 3) == 1) ? g1
                                     : ((k & 3) == 2) ? g2 : g3;
                const int    plv  = k + ((k >> 2) << 4);
                const double piv  = __shfl(myslot, plv, 64);
                const double cv   = __shfl(myslot, ri + ((k >> 2) << 4), 64);
                const double pr0  = __shfl(g0, k + (cg << 4), 64);
                const double pr1  = __shfl(g1, k + (cg << 4), 64);
                const double pr2  = __shfl(g2, k + (cg << 4), 64);
                const double pr3  = __shfl(g3, k + (cg << 4), 64);
                const double ip   = 1.0 / piv;
                const bool   rk   = (ri == k);
                g0 = rk ? ((jb + 0 == k) ? ip : pr0 * ip)
                        : ((jb + 0 == k) ? -cv * ip : g0 - cv * pr0 * ip);
                g1 = rk ? ((jb + 1 == k) ? ip : pr1 * ip)
                        : ((jb + 1 == k) ? -cv * ip : g1 - cv * pr1 * ip);
                g2 = rk ? ((jb + 2 == k) ? ip : pr2 * ip)
                        : ((jb + 2 == k) ? -cv * ip : g2 - cv * pr2 * ip);
                g3 = rk ? ((jb + 3 == k) ? ip : pr3 * ip)
                        : ((jb + 3 == k) ? -cv * ip : g3 - cv * pr3 * ip);
            }
            sGi[ri][jb + 0] = g0; sGi[ri][jb + 1] = g1;
            sGi[ri][jb + 2] = g2; sGi[ri][jb + 3] = g3;
        } else {
            const int e0 = tid - 64;
            for (int e = e0; e < NI * NS; e += 192) {
                const int i = e >> 5, j = e & 31;
                double acc = (double)Ct[j * NA + NS + i];
                for (int k = 0; k < NS; ++k) acc += sB[k][i] * sPA[k][j];
                sHs[i][j] = acc;
            }
            for (int e = e0; e < NS * NS; e += 192) {
                const int i = e >> 5, j = e & 31;
                double acc = (double)Ct[i * NA + j];
                for (int k = 0; k < NS; ++k) acc += sA[k][i] * sPA[k][j];
                sPp[i][j] = acc;
            }
        }
        __syncthreads();
        {
            double a0 = 0, a1 = 0;
            for (int k = 0; k < NI; ++k) {
                const double g = sGi[ki][k];
                a0 += g * sHs[k][kj0 + 0];
                a1 += g * sHs[k][kj0 + 1];
            }
            sKt[ki][kj0 + 0] = a0; sKt[ki][kj0 + 1] = a1;
            if (storeK) {
                sKh[t - kbase][ki][kj0 + 0] = (float)a0;
                sKh[t - kbase][ki][kj0 + 1] = (float)a1;
            }
        }
        __syncthreads();
        {
            double a0 = sPp[pi][pj0 + 0], a1 = sPp[pi][pj0 + 1];
            double a2 = sPp[pi][pj0 + 2], a3 = sPp[pi][pj0 + 3];
            for (int k = 0; k < NI; ++k) {
                const double h = sHs[k][pi];
                a0 -= h * sKt[k][pj0 + 0]; a1 -= h * sKt[k][pj0 + 1];
                a2 -= h * sKt[k][pj0 + 2]; a3 -= h * sKt[k][pj0 + 3];
            }
            double b0 = sPp[pj0 + 0][pi], b1 = sPp[pj0 + 1][pi];
            double b2 = sPp[pj0 + 2][pi], b3 = sPp[pj0 + 3][pi];
            for (int k = 0; k < NI; ++k) {
                const double hk = sKt[k][pi];
                b0 -= sHs[k][pj0 + 0] * hk; b1 -= sHs[k][pj0 + 1] * hk;
                b2 -= sHs[k][pj0 + 2] * hk; b3 -= sHs[k][pj0 + 3] * hk;
            }
            sP[pi][pj0 + 0] = 0.5 * (a0 + b0); sP[pi][pj0 + 1] = 0.5 * (a1 + b1);
            sP[pi][pj0 + 2] = 0.5 * (a2 + b2); sP[pi][pj0 + 3] = 0.5 * (a3 + b3);
        }
        __syncthreads();
        if (emitMu && tid < NS) {
            double acc = 0.0;
            for (int k = 0; k < NS; ++k) acc += sP[tid][k] * (double)sXT[t][k];
            if (t == 0) acc = -acc;
            out[NA * TT + t * NS + tid] = (float)acc;
        }
    };

    auto sweep = [&](int tlo, int klo, int khi, bool emitMu) {
        for (int idx = tid; idx < NS * NS; idx += 256) sP[idx >> 5][idx & 31] = 0.0;
        __syncthreads();
        for (int t = TT - 1; t >= tlo; --t)
            step(t, (t >= klo && t < khi), klo, emitMu);
    };

    int cur = 0;
    auto forward = [&](int t0, int t1, int kbase) {
        for (int t = t0; t < t1; ++t) {
            if (tid < NS) {
                const float xv = (float)sx[cur][tid];
                sXT[t][tid] = xv;
                out[t * NA + tid] = xv;
            } else if (tid >= 64 && tid < 64 + NI) {
                const int i = tid - 64;
                double acc = 0.0;
                for (int k = 0; k < NS; ++k)
                    acc += (double)sKh[t - kbase][i][k] * sx[cur][k];
                su[i] = -acc;
                out[t * NA + NS + i] = (float)(-acc);
            }
            __syncthreads();
            if (t < TT - 1) {
                if (tid < NS) {
                    double acc = 0.0;
                    for (int k = 0; k < NS; ++k) acc += sA[tid][k] * sx[cur][k];
                    for (int k = 0; k < NI; ++k) acc += sB[tid][k] * su[k];
                    sx[cur ^ 1][tid] = acc;
                }
                __syncthreads();
                cur ^= 1;
            }
        }
    };

    sweep(0, 0, HT, false);
    if (tid < NS) sx[0][tid] = (double)x0g[tid];
    __syncthreads();
    forward(0, HT, 0);
    sweep(HT, HT, TT, false);
    forward(HT, TT, HT);
    sweep(0, 0, 0, true);
}

extern "C" void kernel_launch(void* const* d_in, const int* in_sizes, int n_in,
                              void* d_out, int out_size, void* d_ws, size_t ws_size,
                              hipStream_t stream) {
    // Bind by element count (A=1024, B=512, C=147456, x0=32), fallback dict order.
    const float *A = nullptr, *B = nullptr, *C = nullptr, *x0 = nullptr;
    for (int i = 0; i < n_in; ++i) {
        switch (in_sizes[i]) {
            case 1024:   A  = (const float*)d_in[i]; break;
            case 512:    B  = (const float*)d_in[i]; break;
            case 147456: C  = (const float*)d_in[i]; break;
            case 32:     x0 = (const float*)d_in[i]; break;
            default: break;
        }
    }
    if (!A || !B || !C || !x0) {
        A  = (const float*)d_in[0];
        B  = (const float*)d_in[1];
        C  = (const float*)d_in[2];
        x0 = (const float*)d_in[5];
    }

    const size_t need = (size_t)(TT * NI * NS + TT * NS * NS) * sizeof(float); // 384 KB
    if (d_ws != nullptr && ws_size >= need) {
        float* Kall = (float*)d_ws;
        float* Pall = Kall + TT * NI * NS;
        lqr_fast<<<1, 256, 0, stream>>>(A, B, C, x0, (float*)d_out, Kall, Pall);
    } else {
        lqr_kernel_fb<<<1, 256, 0, stream>>>(A, B, C, x0, (float*)d_out);
    }
}

// Round 20
// 526.293 us; speedup vs baseline: 1.1452x; 1.1452x over previous
//
#include <hip/hip_runtime.h>

#define NS 32   // n_state
#define NI 16   // n_input
#define NA 48   // n_all
#define TT 64   // horizon
#define HT 32   // half horizon
#define CSZ (NA * NA)      // 2304 floats per C_t
#define NTRI 528           // upper-triangle pairs of 32x32

// decode linear upper-triangle index e -> (i,j), i<=j  (init-time only)
__device__ __forceinline__ void tri_decode(int e, int& i, int& j) {
    int ii = 0, rem = e;
    while (rem >= NS - ii) { rem -= NS - ii; ++ii; }
    i = ii; j = ii + rem;
}

// ---------------- FAST PATH ----------------
// r17 base (proven best: 543 us; r18 TLP probe and r19 f32-intermediates both
// regressed) + ONE chain-overlap lever: phase-2/phase-4 dot loops fused into
// single k-loops with all per-thread dots as INDEPENDENT accumulator chains
// (pairs decoded once at init into registers; sTri indirection removed).
// Same elements, same ascending-k order -> bit-identical output to r17.
// Mechanism: kernel is dependency-latency-bound (1 wave/SIMD); 6 interleaved
// load->FMA chains hide ds_read latency that a serial for-e loop exposes.
// f64 state/intermediates, f32 A/B in LDS (exact input promotion),
// exact-rcp shfl GJ in wave 0, symmetric-by-construction triangle P update
// (REQUIRED - asymmetric recursion diverges, 126976 signature), 4 barriers,
// K_t/P_t f32 to d_ws, barrier forward rollout, parallel mu pass, f32 out.
__launch_bounds__(256, 1)
__global__ void lqr_fast(const float* __restrict__ Ag,
                         const float* __restrict__ Bg,
                         const float* __restrict__ Cg,
                         const float* __restrict__ x0g,
                         float* __restrict__ out,
                         float* __restrict__ Kall,   // [TT][NI][NS] f32
                         float* __restrict__ Pall)   // [TT][NS][NS] f32
{
    __shared__ float  sXT[TT][NS];      //  8192 B  x trajectory (f32)
    __shared__ float  sA[NS][33];       //  4224 B  A (f32, exact input)
    __shared__ float  sB[NS][17];       //  2176 B  B (f32, exact input)
    __shared__ double sP[NS][33];       //  8448 B  Riccati state (f64)
    __shared__ double sPA[NS][33];      //  8448 B  P*A (f64)
    __shared__ double sPB[NS][17];      //  4352 B  P*B (f64)
    __shared__ double sHs[NI][33];      //  4224 B  S^T + B^T P A (f64)
    __shared__ double sKt[NI][33];      //  4224 B  K_t (f64)
    __shared__ double sGi[NI][17];      //  2176 B  G^{-1} (f64)
    __shared__ double sPp[NS][33];      //  8448 B  Q + A^T P A (f64, symmetric)
    __shared__ double sx[2][NS];        //   512 B
    __shared__ double su[NI];           //   128 B   (~55 KB)

    const int tid  = threadIdx.x;
    const int wid  = tid >> 6, lane = tid & 63;
    const int pi   = tid >> 3, pj0 = (tid & 7) * 4, pb0 = (tid & 7) * 2;
    const int ki   = tid >> 4, kj0 = (tid & 15) * 2;

    // ---- init-time register decoding of all t-invariant work assignments ----
    // phase 2 (threads 64..255): Hs dots at e0, e0+192 (always), e0+384 (if <512)
    //                            Pp tri dots at e0, e0+192 (always), e0+384 (if <528)
    const int e0   = tid - 64;                       // valid when wid>0
    const int hI0_ = (e0 >= 0) ? (e0 >> 5) : 0,        hJ0_ = (e0 >= 0) ? (e0 & 31) : 0;
    const int hI1_ = (e0 >= 0) ? ((e0+192) >> 5) : 0,  hJ1_ = (e0 >= 0) ? ((e0+192) & 31) : 0;
    const bool hasH2 = (e0 >= 0) && (e0 + 384 < 512);
    const int hI2_ = hasH2 ? ((e0+384) >> 5) : 0,      hJ2_ = hasH2 ? ((e0+384) & 31) : 0;
    int pI0_ = 0, pJ0_ = 0, pI1_ = 0, pJ1_ = 0, pI2_ = 0, pJ2_ = 0;
    bool hasP2 = false;
    if (e0 >= 0) {
        tri_decode(e0, pI0_, pJ0_);
        tri_decode(e0 + 192, pI1_, pJ1_);
        hasP2 = (e0 + 384 < NTRI);
        if (hasP2) tri_decode(e0 + 384, pI2_, pJ2_);
    }
    // phase 4 (all 256 threads): tri dots at tid, tid+256 (always), tid+512 (if <528)
    int fI0_, fJ0_, fI1_, fJ1_, fI2_ = 0, fJ2_ = 0;
    tri_decode(tid, fI0_, fJ0_);
    tri_decode(tid + 256, fI1_, fJ1_);
    const bool hasF2 = (tid + 512 < NTRI);   // tid < 16
    if (hasF2) tri_decode(tid + 512, fI2_, fJ2_);

    for (int idx = tid; idx < NS * NS; idx += 256) {
        sA[idx >> 5][idx & 31] = Ag[idx];
        sP[idx >> 5][idx & 31] = 0.0;
    }
    for (int idx = tid; idx < NS * NI; idx += 256)
        sB[idx >> 4][idx & 15] = Bg[idx];
    __syncthreads();

    // ---- backward sweep: 64 steps, 4 barriers each ----
    for (int t = TT - 1; t >= 0; --t) {
        const float* Ct = Cg + t * CSZ;

        // phase 1: PA = P*A (4 cols), PB = P*B (2 cols) per thread (ILP-6)
        {
            double a0 = 0, a1 = 0, a2 = 0, a3 = 0, b0 = 0, b1 = 0;
            for (int k = 0; k < NS; ++k) {
                const double p = sP[pi][k];
                a0 += p * (double)sA[k][pj0 + 0]; a1 += p * (double)sA[k][pj0 + 1];
                a2 += p * (double)sA[k][pj0 + 2]; a3 += p * (double)sA[k][pj0 + 3];
                b0 += p * (double)sB[k][pb0 + 0]; b1 += p * (double)sB[k][pb0 + 1];
            }
            sPA[pi][pj0 + 0] = a0; sPA[pi][pj0 + 1] = a1;
            sPA[pi][pj0 + 2] = a2; sPA[pi][pj0 + 3] = a3;
            sPB[pi][pb0 + 0] = b0; sPB[pi][pb0 + 1] = b1;
        }
        __syncthreads();                                   // barrier A

        // phase 2 (overlapped): wave0 -> G^{-1} (register GJ via __shfl);
        //   waves 1-3 -> 3 Hs + 3 Pp dots per thread, ONE fused k-loop
        //   (6 independent accumulator chains -> latency hiding)
        if (wid == 0) {
            const int ri = lane & 15, cg = lane >> 4, jb = cg * 4;
            double g0 = (double)Ct[(NS + ri) * NA + NS + jb + 0];
            double g1 = (double)Ct[(NS + ri) * NA + NS + jb + 1];
            double g2 = (double)Ct[(NS + ri) * NA + NS + jb + 2];
            double g3 = (double)Ct[(NS + ri) * NA + NS + jb + 3];
            for (int k = 0; k < NS; ++k) {
                const double b = (double)sB[k][ri];
                g0 += b * sPB[k][jb + 0]; g1 += b * sPB[k][jb + 1];
                g2 += b * sPB[k][jb + 2]; g3 += b * sPB[k][jb + 3];
            }
#pragma unroll
            for (int k = 0; k < NI; ++k) {
                const double myslot = ((k & 3) == 0) ? g0 : ((k & 3) == 1) ? g1
                                     : ((k & 3) == 2) ? g2 : g3;
                const int    plv  = k + ((k >> 2) << 4);      // lane of (k,k)
                const double piv  = __shfl(myslot, plv, 64);
                const double cv   = __shfl(myslot, ri + ((k >> 2) << 4), 64); // (ri,k)
                const double pr0  = __shfl(g0, k + (cg << 4), 64);            // (k,jb+j)
                const double pr1  = __shfl(g1, k + (cg << 4), 64);
                const double pr2  = __shfl(g2, k + (cg << 4), 64);
                const double pr3  = __shfl(g3, k + (cg << 4), 64);
                const double ip   = 1.0 / piv;
                const bool   rk   = (ri == k);
                g0 = rk ? ((jb + 0 == k) ? ip : pr0 * ip)
                        : ((jb + 0 == k) ? -cv * ip : g0 - cv * pr0 * ip);
                g1 = rk ? ((jb + 1 == k) ? ip : pr1 * ip)
                        : ((jb + 1 == k) ? -cv * ip : g1 - cv * pr1 * ip);
                g2 = rk ? ((jb + 2 == k) ? ip : pr2 * ip)
                        : ((jb + 2 == k) ? -cv * ip : g2 - cv * pr2 * ip);
                g3 = rk ? ((jb + 3 == k) ? ip : pr3 * ip)
                        : ((jb + 3 == k) ? -cv * ip : g3 - cv * pr3 * ip);
            }
            sGi[ri][jb + 0] = g0; sGi[ri][jb + 1] = g1;
            sGi[ri][jb + 2] = g2; sGi[ri][jb + 3] = g3;
        } else {
            double h0 = (double)Ct[hJ0_ * NA + NS + hI0_];
            double h1 = (double)Ct[hJ1_ * NA + NS + hI1_];
            double h2 = hasH2 ? (double)Ct[hJ2_ * NA + NS + hI2_] : 0.0;
            double q0 = (double)Ct[pI0_ * NA + pJ0_];
            double q1 = (double)Ct[pI1_ * NA + pJ1_];
            double q2 = hasP2 ? (double)Ct[pI2_ * NA + pJ2_] : 0.0;
            for (int k = 0; k < NS; ++k) {
                h0 += (double)sB[k][hI0_] * sPA[k][hJ0_];
                h1 += (double)sB[k][hI1_] * sPA[k][hJ1_];
                h2 += (double)sB[k][hI2_] * sPA[k][hJ2_];
                q0 += (double)sA[k][pI0_] * sPA[k][pJ0_];
                q1 += (double)sA[k][pI1_] * sPA[k][pJ1_];
                q2 += (double)sA[k][pI2_] * sPA[k][pJ2_];
            }
            sHs[hI0_][hJ0_] = h0;
            sHs[hI1_][hJ1_] = h1;
            if (hasH2) sHs[hI2_][hJ2_] = h2;
            sPp[pI0_][pJ0_] = q0; sPp[pJ0_][pI0_] = q0;   // mirrored: exact symmetry
            sPp[pI1_][pJ1_] = q1; sPp[pJ1_][pI1_] = q1;
            if (hasP2) { sPp[pI2_][pJ2_] = q2; sPp[pJ2_][pI2_] = q2; }
        }
        __syncthreads();                                   // barrier B

        // phase 3: K = G^{-1} Hs (2 cols per thread); f32 K to d_ws
        {
            double a0 = 0, a1 = 0;
            for (int k = 0; k < NI; ++k) {
                const double g = sGi[ki][k];
                a0 += g * sHs[k][kj0 + 0];
                a1 += g * sHs[k][kj0 + 1];
            }
            sKt[ki][kj0 + 0] = a0; sKt[ki][kj0 + 1] = a1;
            Kall[t * NI * NS + ki * NS + kj0 + 0] = (float)a0;
            Kall[t * NI * NS + ki * NS + kj0 + 1] = (float)a1;
        }
        __syncthreads();                                   // barrier C

        // phase 4: P = Pp - Hs^T K on the upper triangle (2-3 fused dots),
        // write both slots (exact symmetry by construction)
        {
            double a0 = sPp[fI0_][fJ0_];
            double a1 = sPp[fI1_][fJ1_];
            double a2 = hasF2 ? sPp[fI2_][fJ2_] : 0.0;
            for (int k = 0; k < NI; ++k) {
                a0 -= sHs[k][fI0_] * sKt[k][fJ0_];
                a1 -= sHs[k][fI1_] * sKt[k][fJ1_];
                a2 -= sHs[k][fI2_] * sKt[k][fJ2_];
            }
            sP[fI0_][fJ0_] = a0; sP[fJ0_][fI0_] = a0;
            sP[fI1_][fJ1_] = a1; sP[fJ1_][fI1_] = a1;
            float* Pt = Pall + t * NS * NS;
            Pt[fI0_ * NS + fJ0_] = (float)a0; Pt[fJ0_ * NS + fI0_] = (float)a0;
            Pt[fI1_ * NS + fJ1_] = (float)a1; Pt[fJ1_ * NS + fI1_] = (float)a1;
            if (hasF2) {
                sP[fI2_][fJ2_] = a2; sP[fJ2_][fI2_] = a2;
                Pt[fI2_ * NS + fJ2_] = (float)a2; Pt[fJ2_ * NS + fI2_] = (float)a2;
            }
        }
        __syncthreads();                                   // barrier D
    }

    // ---- forward rollout: tau (x + u), record x trajectory ----
    if (tid < NS) sx[0][tid] = (double)x0g[tid];
    __syncthreads();
    int cur = 0;
    for (int t = 0; t < TT; ++t) {
        if (tid < NS) {
            const float xv = (float)sx[cur][tid];
            sXT[t][tid] = xv;
            out[t * NA + tid] = xv;
        } else if (tid >= 64 && tid < 64 + NI) {
            const int i = tid - 64;
            const float* Kt = Kall + t * NI * NS + i * NS;
            double acc = 0.0;
            for (int k = 0; k < NS; ++k) acc += (double)Kt[k] * sx[cur][k];
            su[i] = -acc;
            out[t * NA + NS + i] = (float)(-acc);
        }
        __syncthreads();
        if (t < TT - 1) {
            if (tid < NS) {
                double acc = 0.0;
                for (int k = 0; k < NS; ++k) acc += (double)sA[tid][k] * sx[cur][k];
                for (int k = 0; k < NI; ++k) acc += (double)sB[tid][k] * su[k];
                sx[cur ^ 1][tid] = acc;
            }
            __syncthreads();
            cur ^= 1;
        }
    }
    __syncthreads();

    // ---- mu pass: mu_t = P_t x_t (2048 parallel dots); mu_0 negated ----
    for (int e = tid; e < TT * NS; e += 256) {
        const int t = e >> 5, i = e & 31;
        const float* Pt = Pall + t * NS * NS + i * NS;
        double acc = 0.0;
        for (int k = 0; k < NS; ++k) acc += (double)Pt[k] * (double)sXT[t][k];
        if (t == 0) acc = -acc;
        out[NA * TT + t * NS + i] = (float)acc;
    }
}

// ---------------- FALLBACK (round-11/12, passing) — if ws_size < 384 KB ----
__launch_bounds__(256, 1)
__global__ void lqr_kernel_fb(const float* __restrict__ Ag,
                              const float* __restrict__ Bg,
                              const float* __restrict__ Cg,
                              const float* __restrict__ x0g,
                              float* __restrict__ out)
{
    __shared__ float  sKh[HT][NI][NS];
    __shared__ float  sXT[TT][NS];
    __shared__ double sA[NS][NS];
    __shared__ double sB[NS][NI];
    __shared__ double sP[NS][NS];
    __shared__ double sPA[NS][NS];
    __shared__ double sPB[NS][NI];
    __shared__ double sHs[NI][NS];
    __shared__ double sKt[NI][NS];
    __shared__ double sGi[NI][NI];
    __shared__ double sPp[NS][NS];
    __shared__ double sx[2][NS];
    __shared__ double su[NI];

    const int tid  = threadIdx.x;
    const int wid  = tid >> 6, lane = tid & 63;
    const int pi   = tid >> 3, pj0 = (tid & 7) * 4, pb0 = (tid & 7) * 2;
    const int ki   = tid >> 4, kj0 = (tid & 15) * 2;

    for (int idx = tid; idx < NS * NS; idx += 256) sA[idx >> 5][idx & 31] = (double)Ag[idx];
    for (int idx = tid; idx < NS * NI; idx += 256) sB[idx >> 4][idx & 15] = (double)Bg[idx];
    __syncthreads();

    auto step = [&](int t, bool storeK, int kbase, bool emitMu) {
        const float* Ct = Cg + t * NA * NA;
        {
            double a0 = 0, a1 = 0, a2 = 0, a3 = 0, b0 = 0, b1 = 0;
            for (int k = 0; k < NS; ++k) {
                const double p = sP[pi][k];
                a0 += p * sA[k][pj0 + 0]; a1 += p * sA[k][pj0 + 1];
                a2 += p * sA[k][pj0 + 2]; a3 += p * sA[k][pj0 + 3];
                b0 += p * sB[k][pb0 + 0]; b1 += p * sB[k][pb0 + 1];
            }
            sPA[pi][pj0 + 0] = a0; sPA[pi][pj0 + 1] = a1;
            sPA[pi][pj0 + 2] = a2; sPA[pi][pj0 + 3] = a3;
            sPB[pi][pb0 + 0] = b0; sPB[pi][pb0 + 1] = b1;
        }
        __syncthreads();
        if (wid == 0) {
            const int ri = lane & 15, cg = lane >> 4, jb = cg * 4;
            double g0 = (double)Ct[(NS + ri) * NA + NS + jb + 0];
            double g1 = (double)Ct[(NS + ri) * NA + NS + jb + 1];
            double g2 = (double)Ct[(NS + ri) * NA + NS + jb + 2];
            double g3 = (double)Ct[(NS + ri) * NA + NS + jb + 3];
            for (int k = 0; k < NS; ++k) {
                const double b = sB[k][ri];
                g0 += b * sPB[k][jb + 0]; g1 += b * sPB[k][jb + 1];
                g2 += b * sPB[k][jb + 2]; g3 += b * sPB[k][jb + 3];
            }
#pragma unroll
            for (int k = 0; k < NI; ++k) {
                const double myslot = ((k & 3) == 0) ? g0 : ((k & 3) == 1) ? g1
                                     : ((k & 3) == 2) ? g2 : g3;
                const int    plv  = k + ((k >> 2) << 4);
                const double piv  = __shfl(myslot, plv, 64);
                const double cv   = __shfl(myslot, ri + ((k >> 2) << 4), 64);
                const double pr0  = __shfl(g0, k + (cg << 4), 64);
                const double pr1  = __shfl(g1, k + (cg << 4), 64);
                const double pr2  = __shfl(g2, k + (cg << 4), 64);
                const double pr3  = __shfl(g3, k + (cg << 4), 64);
                const double ip   = 1.0 / piv;
                const bool   rk   = (ri == k);
                g0 = rk ? ((jb + 0 == k) ? ip : pr0 * ip)
                        : ((jb + 0 == k) ? -cv * ip : g0 - cv * pr0 * ip);
                g1 = rk ? ((jb + 1 == k) ? ip : pr1 * ip)
                        : ((jb + 1 == k) ? -cv * ip : g1 - cv * pr1 * ip);
                g2 = rk ? ((jb + 2 == k) ? ip : pr2 * ip)
                        : ((jb + 2 == k) ? -cv * ip : g2 - cv * pr2 * ip);
                g3 = rk ? ((jb + 3 == k) ? ip : pr3 * ip)
                        : ((jb + 3 == k) ? -cv * ip : g3 - cv * pr3 * ip);
            }
            sGi[ri][jb + 0] = g0; sGi[ri][jb + 1] = g1;
            sGi[ri][jb + 2] = g2; sGi[ri][jb + 3] = g3;
        } else {
            const int e0 = tid - 64;
            for (int e = e0; e < NI * NS; e += 192) {
                const int i = e >> 5, j = e & 31;
                double acc = (double)Ct[j * NA + NS + i];
                for (int k = 0; k < NS; ++k) acc += sB[k][i] * sPA[k][j];
                sHs[i][j] = acc;
            }
            for (int e = e0; e < NS * NS; e += 192) {
                const int i = e >> 5, j = e & 31;
                double acc = (double)Ct[i * NA + j];
                for (int k = 0; k < NS; ++k) acc += sA[k][i] * sPA[k][j];
                sPp[i][j] = acc;
            }
        }
        __syncthreads();
        {
            double a0 = 0, a1 = 0;
            for (int k = 0; k < NI; ++k) {
                const double g = sGi[ki][k];
                a0 += g * sHs[k][kj0 + 0];
                a1 += g * sHs[k][kj0 + 1];
            }
            sKt[ki][kj0 + 0] = a0; sKt[ki][kj0 + 1] = a1;
            if (storeK) {
                sKh[t - kbase][ki][kj0 + 0] = (float)a0;
                sKh[t - kbase][ki][kj0 + 1] = (float)a1;
            }
        }
        __syncthreads();
        {
            double a0 = sPp[pi][pj0 + 0], a1 = sPp[pi][pj0 + 1];
            double a2 = sPp[pi][pj0 + 2], a3 = sPp[pi][pj0 + 3];
            for (int k = 0; k < NI; ++k) {
                const double h = sHs[k][pi];
                a0 -= h * sKt[k][pj0 + 0]; a1 -= h * sKt[k][pj0 + 1];
                a2 -= h * sKt[k][pj0 + 2]; a3 -= h * sKt[k][pj0 + 3];
            }
            double b0 = sPp[pj0 + 0][pi], b1 = sPp[pj0 + 1][pi];
            double b2 = sPp[pj0 + 2][pi], b3 = sPp[pj0 + 3][pi];
            for (int k = 0; k < NI; ++k) {
                const double hk = sKt[k][pi];
                b0 -= sHs[k][pj0 + 0] * hk; b1 -= sHs[k][pj0 + 1] * hk;
                b2 -= sHs[k][pj0 + 2] * hk; b3 -= sHs[k][pj0 + 3] * hk;
            }
            sP[pi][pj0 + 0] = 0.5 * (a0 + b0); sP[pi][pj0 + 1] = 0.5 * (a1 + b1);
            sP[pi][pj0 + 2] = 0.5 * (a2 + b2); sP[pi][pj0 + 3] = 0.5 * (a3 + b3);
        }
        __syncthreads();
        if (emitMu && tid < NS) {
            double acc = 0.0;
            for (int k = 0; k < NS; ++k) acc += sP[tid][k] * (double)sXT[t][k];
            if (t == 0) acc = -acc;
            out[NA * TT + t * NS + tid] = (float)acc;
        }
    };

    auto sweep = [&](int tlo, int klo, int khi, bool emitMu) {
        for (int idx = tid; idx < NS * NS; idx += 256) sP[idx >> 5][idx & 31] = 0.0;
        __syncthreads();
        for (int t = TT - 1; t >= tlo; --t)
            step(t, (t >= klo && t < khi), klo, emitMu);
    };

    int cur = 0;
    auto forward = [&](int t0, int t1, int kbase) {
        for (int t = t0; t < t1; ++t) {
            if (tid < NS) {
                const float xv = (float)sx[cur][tid];
                sXT[t][tid] = xv;
                out[t * NA + tid] = xv;
            } else if (tid >= 64 && tid < 64 + NI) {
                const int i = tid - 64;
                double acc = 0.0;
                for (int k = 0; k < NS; ++k)
                    acc += (double)sKh[t - kbase][i][k] * sx[cur][k];
                su[i] = -acc;
                out[t * NA + NS + i] = (float)(-acc);
            }
            __syncthreads();
            if (t < TT - 1) {
                if (tid < NS) {
                    double acc = 0.0;
                    for (int k = 0; k < NS; ++k) acc += sA[tid][k] * sx[cur][k];
                    for (int k = 0; k < NI; ++k) acc += sB[tid][k] * su[k];
                    sx[cur ^ 1][tid] = acc;
                }
                __syncthreads();
                cur ^= 1;
            }
        }
    };

    sweep(0, 0, HT, false);
    if (tid < NS) sx[0][tid] = (double)x0g[tid];
    __syncthreads();
    forward(0, HT, 0);
    sweep(HT, HT, TT, false);
    forward(HT, TT, HT);
    sweep(0, 0, 0, true);
}

extern "C" void kernel_launch(void* const* d_in, const int* in_sizes, int n_in,
                              void* d_out, int out_size, void* d_ws, size_t ws_size,
                              hipStream_t stream) {
    // Bind by element count (A=1024, B=512, C=147456, x0=32), fallback dict order.
    const float *A = nullptr, *B = nullptr, *C = nullptr, *x0 = nullptr;
    for (int i = 0; i < n_in; ++i) {
        switch (in_sizes[i]) {
            case 1024:   A  = (const float*)d_in[i]; break;
            case 512:    B  = (const float*)d_in[i]; break;
            case 147456: C  = (const float*)d_in[i]; break;
            case 32:     x0 = (const float*)d_in[i]; break;
            default: break;
        }
    }
    if (!A || !B || !C || !x0) {
        A  = (const float*)d_in[0];
        B  = (const float*)d_in[1];
        C  = (const float*)d_in[2];
        x0 = (const float*)d_in[5];
    }

    const size_t need = (size_t)(TT * NI * NS + TT * NS * NS) * sizeof(float); // 384 KB
    if (d_ws != nullptr && ws_size >= need) {
        float* Kall = (float*)d_ws;
        float* Pall = Kall + TT * NI * NS;
        lqr_fast<<<1, 256, 0, stream>>>(A, B, C, x0, (float*)d_out, Kall, Pall);
    } else {
        lqr_kernel_fb<<<1, 256, 0, stream>>>(A, B, C, x0, (float*)d_out);
    }
}